// Round 1
// baseline (836.347 us; speedup 1.0000x reference)
//
#include <hip/hip_runtime.h>
#include <cfloat>

// kNNSelfAttention on MI355X.
// Key reduction: softmax(mask*score) with multiplicative -1e19 mask is exactly
// one-hot at argmin_m score[n,m] (most negative score -> +1e19*|score| after
// masking dominates). So attention = one-hot(argmin), h[n] = xp[argmin].
// Top-k adjacency provably never affects the output.

#define TILE_K 32
#define LDSR 68  // 64 + 4 pad (floats) -> 16B-aligned rows, conflict-light

// Load a 64-row x 32-k f32 tile from row-major src (ld=512) into k-major LDS [32][LDSR].
__device__ __forceinline__ void load_tile64x32(const float* __restrict__ src,
                                               int rowbase, int kbase,
                                               float* lds, int tid) {
  const int klane = tid & 7;   // 0..7 -> k offset 4*klane
  const int row = tid >> 3;    // 0..31
#pragma unroll
  for (int p = 0; p < 2; ++p) {
    const int r = row + p * 32;
    const float4 v = *reinterpret_cast<const float4*>(
        src + (size_t)(rowbase + r) * 512 + kbase + 4 * klane);
    float* d = lds + r + (4 * klane) * LDSR;
    d[0 * LDSR] = v.x;
    d[1 * LDSR] = v.y;
    d[2 * LDSR] = v.z;
    d[3 * LDSR] = v.w;
  }
}

// xp[bn, o] = sum_l x[bn, l] * W[o, l]   (A*B^T, both row-major, K=512)
__global__ __launch_bounds__(256) void gemm_xw_kernel(const float* __restrict__ x,
                                                      const float* __restrict__ W,
                                                      float* __restrict__ xp) {
  __shared__ float lA[TILE_K * LDSR];
  __shared__ float lB[TILE_K * LDSR];
  const int tid = threadIdx.x;
  const int tx = tid & 15, ty = tid >> 4;
  const int nbase = blockIdx.x * 64;  // over 16384 rows
  const int obase = blockIdx.y * 64;  // over 512 cols
  float acc[4][4] = {};
  for (int kb = 0; kb < 512; kb += TILE_K) {
    load_tile64x32(x, nbase, kb, lA, tid);
    load_tile64x32(W, obase, kb, lB, tid);
    __syncthreads();
#pragma unroll
    for (int k = 0; k < TILE_K; ++k) {
      const float4 a4 = *reinterpret_cast<const float4*>(&lA[k * LDSR + 4 * ty]);
      const float4 b4 = *reinterpret_cast<const float4*>(&lB[k * LDSR + 4 * tx]);
      const float a[4] = {a4.x, a4.y, a4.z, a4.w};
      const float b[4] = {b4.x, b4.y, b4.z, b4.w};
#pragma unroll
      for (int i = 0; i < 4; ++i)
#pragma unroll
        for (int j = 0; j < 4; ++j) acc[i][j] = fmaf(a[i], b[j], acc[i][j]);
    }
    __syncthreads();
  }
#pragma unroll
  for (int i = 0; i < 4; ++i) {
    const float4 v = {acc[i][0], acc[i][1], acc[i][2], acc[i][3]};
    *reinterpret_cast<float4*>(xp + (size_t)(nbase + 4 * ty + i) * 512 + obase + 4 * tx) = v;
  }
}

// Per batch b: for each row n in this block's 64-row tile, find
// argmin_m dot(xp[b,n,:], xp[b,m,:]) over all m in [0,2048); then
// attention[b,n,argmin]=1 and h[b,n,:]=xp[b,argmin,:].
__global__ __launch_bounds__(256) void score_argmin_kernel(const float* __restrict__ xp,
                                                           float* __restrict__ h,
                                                           float* __restrict__ att) {
  __shared__ float lA[TILE_K * LDSR];
  __shared__ float lB[TILE_K * LDSR];
  __shared__ int sIdx[64];
  const int tid = threadIdx.x;
  const int tx = tid & 15, ty = tid >> 4;
  const int b = blockIdx.x & 7;       // batch -> XCD locality (xp_b = 4MB fits L2)
  const int ntile = blockIdx.x >> 3;  // 0..31
  const int nbase = ntile * 64;
  const float* Xb = xp + (size_t)b * 2048 * 512;

  float rMin[4] = {FLT_MAX, FLT_MAX, FLT_MAX, FLT_MAX};
  int rIdx[4] = {0, 0, 0, 0};

  for (int mt = 0; mt < 32; ++mt) {
    const int mbase = mt * 64;
    float acc[4][4] = {};
    for (int kb = 0; kb < 512; kb += TILE_K) {
      load_tile64x32(Xb, nbase, kb, lA, tid);
      load_tile64x32(Xb, mbase, kb, lB, tid);
      __syncthreads();
#pragma unroll
      for (int k = 0; k < TILE_K; ++k) {
        const float4 a4 = *reinterpret_cast<const float4*>(&lA[k * LDSR + 4 * ty]);
        const float4 b4 = *reinterpret_cast<const float4*>(&lB[k * LDSR + 4 * tx]);
        const float a[4] = {a4.x, a4.y, a4.z, a4.w};
        const float bb[4] = {b4.x, b4.y, b4.z, b4.w};
#pragma unroll
        for (int i = 0; i < 4; ++i)
#pragma unroll
          for (int j = 0; j < 4; ++j) acc[i][j] = fmaf(a[i], bb[j], acc[i][j]);
      }
      __syncthreads();
    }
    // min-reduce this 64-col slab into running (val, idx) per row
#pragma unroll
    for (int i = 0; i < 4; ++i) {
      float v = acc[i][0];
      int idx = mbase + 4 * tx;
#pragma unroll
      for (int j = 1; j < 4; ++j) {
        const int cand = mbase + 4 * tx + j;
        if (acc[i][j] < v) { v = acc[i][j]; idx = cand; }
      }
      // butterfly over the 16 lanes sharing this row (tx = tid&15)
#pragma unroll
      for (int off = 1; off < 16; off <<= 1) {
        const float ov = __shfl_xor(v, off);
        const int oi = __shfl_xor(idx, off);
        if (ov < v || (ov == v && oi < idx)) { v = ov; idx = oi; }
      }
      if (v < rMin[i] || (v == rMin[i] && idx < rIdx[i])) { rMin[i] = v; rIdx[i] = idx; }
    }
  }

  if (tx == 0) {
#pragma unroll
    for (int i = 0; i < 4; ++i) sIdx[4 * ty + i] = rIdx[i];
  }
  __syncthreads();

  // attention: one-hot scatter (buffer was zeroed via hipMemsetAsync)
  if (tid < 64) {
    att[((size_t)b * 2048 + nbase + tid) * 2048 + sIdx[tid]] = 1.0f;
  }
  // h: gather rows xp[b, argmin, :]
  const int wid = tid >> 6, lane = tid & 63;
  for (int r = wid; r < 64; r += 4) {
    const float4* srcv = reinterpret_cast<const float4*>(Xb + (size_t)sIdx[r] * 512);
    float4* dstv = reinterpret_cast<float4*>(h + ((size_t)b * 2048 + nbase + r) * 512);
#pragma unroll
    for (int c = 0; c < 2; ++c) dstv[lane + 64 * c] = srcv[lane + 64 * c];
  }
}

extern "C" void kernel_launch(void* const* d_in, const int* in_sizes, int n_in,
                              void* d_out, int out_size, void* d_ws, size_t ws_size,
                              hipStream_t stream) {
  const float* x = (const float*)d_in[0];  // [8, 2048, 512] f32
  const float* W = (const float*)d_in[1];  // [512, 512] f32
  float* out = (float*)d_out;
  float* h = out;                                   // [8, 2048, 512]
  float* att = out + (size_t)8 * 2048 * 512;        // [8, 2048, 2048]
  float* xp = (float*)d_ws;                         // [8*2048, 512] f32 = 32 MB

  // 1) xp = x @ W^T
  dim3 gridA(16384 / 64, 512 / 64);
  hipLaunchKernelGGL(gemm_xw_kernel, gridA, dim3(256), 0, stream, x, W, xp);

  // 2) attention := 0 (then scatter ones in kernel B)
  hipMemsetAsync(att, 0, (size_t)8 * 2048 * 2048 * sizeof(float), stream);

  // 3) fused score + row-argmin + outputs
  hipLaunchKernelGGL(score_argmin_kernel, dim3(256), dim3(256), 0, stream, xp, h, att);
}

// Round 2
// 601.073 us; speedup vs baseline: 1.3914x; 1.3914x over previous
//
#include <hip/hip_runtime.h>
#include <cfloat>

// kNNSelfAttention: softmax(mask*score) with multiplicative -1e19 mask is exactly
// one-hot at argmin_m score[n,m] (validated round 1, absmax 0.0).
//   K1: xp = x@W^T in exact f32 (feeds h and the exact rescore) + bf16 copy
//   K2: bf16 MFMA score GEMM, fused per-row top-2 per 64-col slab -> 64 cands/row
//   K3: approx-top-8 of cands, exact f32 rescore, argmin -> write att row + h row
// Scratch: cand lives in each row's own h storage (no cross-block race);
// xp16 lives in the att-region tail (dead before att is written). ws = 32MB only.

typedef short bf16x8 __attribute__((ext_vector_type(8)));
typedef float f32x4 __attribute__((ext_vector_type(4)));

#define TILE_K 32
#define LDSR 68  // 64 + 4 pad floats

__device__ __forceinline__ unsigned short f2bf(float f) {
  unsigned int u = __float_as_uint(f);
  unsigned int r = (u + 0x7FFFu + ((u >> 16) & 1u)) >> 16;  // RNE
  return (unsigned short)r;
}

__device__ __forceinline__ void load_tile64x32(const float* __restrict__ src,
                                               int rowbase, int kbase,
                                               float* lds, int tid) {
  const int klane = tid & 7;
  const int row = tid >> 3;
#pragma unroll
  for (int p = 0; p < 2; ++p) {
    const int r = row + p * 32;
    const float4 v = *reinterpret_cast<const float4*>(
        src + (size_t)(rowbase + r) * 512 + kbase + 4 * klane);
    float* d = lds + r + (4 * klane) * LDSR;
    d[0 * LDSR] = v.x;
    d[1 * LDSR] = v.y;
    d[2 * LDSR] = v.z;
    d[3 * LDSR] = v.w;
  }
}

// K1: xp[bn,o] = sum_l x[bn,l]*W[o,l]; also emit bf16 copy xp16.
__global__ __launch_bounds__(256) void gemm_xw_kernel(const float* __restrict__ x,
                                                      const float* __restrict__ W,
                                                      float* __restrict__ xp,
                                                      unsigned short* __restrict__ xp16) {
  __shared__ float lA[TILE_K * LDSR];
  __shared__ float lB[TILE_K * LDSR];
  const int tid = threadIdx.x;
  const int tx = tid & 15, ty = tid >> 4;
  const int nbase = blockIdx.x * 64;
  const int obase = blockIdx.y * 64;
  float acc[4][4] = {};
  for (int kb = 0; kb < 512; kb += TILE_K) {
    load_tile64x32(x, nbase, kb, lA, tid);
    load_tile64x32(W, obase, kb, lB, tid);
    __syncthreads();
#pragma unroll
    for (int k = 0; k < TILE_K; ++k) {
      const float4 a4 = *reinterpret_cast<const float4*>(&lA[k * LDSR + 4 * ty]);
      const float4 b4 = *reinterpret_cast<const float4*>(&lB[k * LDSR + 4 * tx]);
      const float a[4] = {a4.x, a4.y, a4.z, a4.w};
      const float b[4] = {b4.x, b4.y, b4.z, b4.w};
#pragma unroll
      for (int i = 0; i < 4; ++i)
#pragma unroll
        for (int j = 0; j < 4; ++j) acc[i][j] = fmaf(a[i], b[j], acc[i][j]);
    }
    __syncthreads();
  }
#pragma unroll
  for (int i = 0; i < 4; ++i) {
    const size_t row = (size_t)(nbase + 4 * ty + i);
    const float4 v = {acc[i][0], acc[i][1], acc[i][2], acc[i][3]};
    *reinterpret_cast<float4*>(xp + row * 512 + obase + 4 * tx) = v;
    ushort4 u = {f2bf(acc[i][0]), f2bf(acc[i][1]), f2bf(acc[i][2]), f2bf(acc[i][3])};
    *reinterpret_cast<ushort4*>(xp16 + row * 512 + obase + 4 * tx) = u;
  }
}

__device__ __forceinline__ void ins2(float& v1, int& c1, float& v2, int& c2,
                                     float v, int c) {
  if (v < v1 || (v == v1 && c < c1)) {
    v2 = v1; c2 = c1; v1 = v; c1 = c;
  } else if (v < v2 || (v == v2 && c < c2)) {
    v2 = v; c2 = c;
  }
}

// K2: one wave per 64x64 score tile; bf16 MFMA; per-row top-2 of this slab.
__global__ __launch_bounds__(64) void score_kernel(const unsigned short* __restrict__ xp16,
                                                   float* __restrict__ cand) {
  const int l = threadIdx.x;
  const int b = blockIdx.x & 7;        // batch -> XCD pin (xp16_b = 2MB, L2-resident)
  const int rem = blockIdx.x >> 3;
  const int ntile = rem & 31;
  const int mtile = rem >> 5;
  const int nbase = ntile * 64, mbase = mtile * 64;
  const unsigned short* Xb = xp16 + (size_t)b * 2048 * 512;
  const int lr = l & 15;   // row within 16-frag (A and B operands)
  const int kg = l >> 4;   // k-group (8 elems each)

  f32x4 acc[4][4] = {};
  const unsigned short* An = Xb + (size_t)(nbase + lr) * 512 + kg * 8;
  const unsigned short* Bm = Xb + (size_t)(mbase + lr) * 512 + kg * 8;

#pragma unroll 2
  for (int kk = 0; kk < 16; ++kk) {
    bf16x8 af[4], bf[4];
#pragma unroll
    for (int i = 0; i < 4; ++i) {
      af[i] = *reinterpret_cast<const bf16x8*>(An + (size_t)i * 16 * 512 + kk * 32);
      bf[i] = *reinterpret_cast<const bf16x8*>(Bm + (size_t)i * 16 * 512 + kk * 32);
    }
#pragma unroll
    for (int i = 0; i < 4; ++i)
#pragma unroll
      for (int j = 0; j < 4; ++j)
        acc[i][j] = __builtin_amdgcn_mfma_f32_16x16x32_bf16(af[i], bf[j], acc[i][j], 0, 0, 0);
  }

  // Epilogue: C layout row=(l>>4)*4+reg, col=l&15 (per 16x16 frag).
#pragma unroll
  for (int i = 0; i < 4; ++i) {
#pragma unroll
    for (int r = 0; r < 4; ++r) {
      float v1 = FLT_MAX, v2 = FLT_MAX;
      int c1 = 0x7fffffff, c2 = 0x7fffffff;
#pragma unroll
      for (int j = 0; j < 4; ++j) ins2(v1, c1, v2, c2, acc[i][j][r], mbase + 16 * j + lr);
#pragma unroll
      for (int off = 1; off < 16; off <<= 1) {
        const float ov1 = __shfl_xor(v1, off); const int oc1 = __shfl_xor(c1, off);
        const float ov2 = __shfl_xor(v2, off); const int oc2 = __shfl_xor(c2, off);
        ins2(v1, c1, v2, c2, ov1, oc1);
        ins2(v1, c1, v2, c2, ov2, oc2);
      }
      if (lr == 0) {
        const int n = nbase + 16 * i + 4 * kg + r;
        const float4 outv = {v1, __int_as_float(c1), v2, __int_as_float(c2)};
        *reinterpret_cast<float4*>(cand + ((size_t)b * 2048 + n) * 512 + 4 * mtile) = outv;
      }
    }
  }
}

// K3: per row: approx-top-8 of 64 cands -> exact f32 rescore -> argmin.
// Writes the full att row (no memset needed) and the h row.
__global__ __launch_bounds__(64) void finalize_kernel(const float* __restrict__ xp,
                                                      float* __restrict__ h,
                                                      float* __restrict__ att) {
  const int l = threadIdx.x;
  const int b = blockIdx.x & 7;        // batch -> XCD pin
  const int n = blockIdx.x >> 3;
  const size_t r = (size_t)b * 2048 + n;

  // own-row candidate scratch (written by K2 into h region)
  const float2 cc = reinterpret_cast<const float2*>(h + r * 512)[l];
  float cv = cc.x;
  int ci = __float_as_int(cc.y);

  int wsel[8];
#pragma unroll
  for (int t = 0; t < 8; ++t) {
    float mv = cv; int mi = ci;
#pragma unroll
    for (int off = 1; off < 64; off <<= 1) {
      const float ov = __shfl_xor(mv, off); const int oi = __shfl_xor(mi, off);
      if (ov < mv || (ov == mv && oi < mi)) { mv = ov; mi = oi; }
    }
    wsel[t] = mi;
    if (ci == mi) cv = FLT_MAX;  // invalidate winner (indices unique)
  }

  const float* xb = xp + (size_t)b * 2048 * 512;
  const float* xn = xb + (size_t)n * 512;
  const float4 q0 = reinterpret_cast<const float4*>(xn)[2 * l];
  const float4 q1 = reinterpret_cast<const float4*>(xn)[2 * l + 1];

  float bestv = FLT_MAX; int besti = 0x7fffffff;
#pragma unroll
  for (int t = 0; t < 8; ++t) {
    const float* xm = xb + (size_t)wsel[t] * 512;
    const float4 p0 = reinterpret_cast<const float4*>(xm)[2 * l];
    const float4 p1 = reinterpret_cast<const float4*>(xm)[2 * l + 1];
    float s = 0.f;
    s = fmaf(q0.x, p0.x, s); s = fmaf(q0.y, p0.y, s);
    s = fmaf(q0.z, p0.z, s); s = fmaf(q0.w, p0.w, s);
    s = fmaf(q1.x, p1.x, s); s = fmaf(q1.y, p1.y, s);
    s = fmaf(q1.z, p1.z, s); s = fmaf(q1.w, p1.w, s);
#pragma unroll
    for (int off = 1; off < 64; off <<= 1) s += __shfl_xor(s, off);
    if (s < bestv || (s == bestv && wsel[t] < besti)) { bestv = s; besti = wsel[t]; }
  }

  // h row = xp[b, besti, :]
  const float* xs = xb + (size_t)besti * 512;
  const float4 w0 = reinterpret_cast<const float4*>(xs)[2 * l];
  const float4 w1 = reinterpret_cast<const float4*>(xs)[2 * l + 1];
  float* hrow = h + r * 512;
  reinterpret_cast<float4*>(hrow)[2 * l] = w0;
  reinterpret_cast<float4*>(hrow)[2 * l + 1] = w1;

  // att row: zeros + one-hot at besti
  float* arow = att + r * 2048;
#pragma unroll
  for (int s = 0; s < 8; ++s) {
    const int cbase = s * 256 + l * 4;
    float4 v;
    v.x = (cbase + 0 == besti) ? 1.0f : 0.0f;
    v.y = (cbase + 1 == besti) ? 1.0f : 0.0f;
    v.z = (cbase + 2 == besti) ? 1.0f : 0.0f;
    v.w = (cbase + 3 == besti) ? 1.0f : 0.0f;
    reinterpret_cast<float4*>(arow)[s * 64 + l] = v;
  }
}

extern "C" void kernel_launch(void* const* d_in, const int* in_sizes, int n_in,
                              void* d_out, int out_size, void* d_ws, size_t ws_size,
                              hipStream_t stream) {
  const float* x = (const float*)d_in[0];  // [8,2048,512] f32
  const float* W = (const float*)d_in[1];  // [512,512] f32
  float* out = (float*)d_out;
  float* h = out;                              // [8,2048,512]
  float* att = out + (size_t)8 * 2048 * 512;   // [8,2048,2048]
  float* xp = (float*)d_ws;                    // 32 MB f32
  // bf16 xp in the LAST 16MB of the att region (dead before att is written)
  unsigned short* xp16 = (unsigned short*)(att + ((size_t)32 - 4) * 1024 * 1024);

  dim3 gridA(16384 / 64, 512 / 64);
  hipLaunchKernelGGL(gemm_xw_kernel, gridA, dim3(256), 0, stream, x, W, xp, xp16);

  // cand scratch = first 512B of each h row
  hipLaunchKernelGGL(score_kernel, dim3(8 * 32 * 32), dim3(64), 0, stream, xp16, h);

  hipLaunchKernelGGL(finalize_kernel, dim3(16384), dim3(64), 0, stream, xp, h, att);
}

// Round 3
// 534.121 us; speedup vs baseline: 1.5658x; 1.1253x over previous
//
#include <hip/hip_runtime.h>
#include <cfloat>

// kNNSelfAttention: softmax(mask*score) with multiplicative -1e19 mask is exactly
// one-hot at argmin_m score[n,m] (validated rounds 1-2, absmax 0.0).
//   K1: xp = x@W^T in exact f32 (feeds h and exact rescore) + bf16 copy
//   K2: bf16 MFMA score GEMM (m97-structure: 128x128 tile, global_load_lds,
//       4 waves) with fused per-row top-2 per 64-col slab -> 64 cands/row
//   K3: approx-top-8 of cands, exact f32 rescore, argmin -> att row + h row
// Scratch: cand lives in each row's own h storage (no cross-block race);
// xp16 lives in the att-region tail (dead before att is written). ws = 32MB.

typedef short bf16x8 __attribute__((ext_vector_type(8)));
typedef float f32x4 __attribute__((ext_vector_type(4)));

#define TILE_K 32
#define LDSR 68  // 64 + 4 pad floats (K1 f32 tiles)

__device__ __forceinline__ unsigned short f2bf(float f) {
  unsigned int u = __float_as_uint(f);
  unsigned int r = (u + 0x7FFFu + ((u >> 16) & 1u)) >> 16;  // RNE
  return (unsigned short)r;
}

__device__ __forceinline__ void gload_lds16(const unsigned short* g, unsigned short* l) {
  __builtin_amdgcn_global_load_lds(
      (const __attribute__((address_space(1))) unsigned int*)g,
      (__attribute__((address_space(3))) unsigned int*)l, 16, 0, 0);
}

__device__ __forceinline__ void load_tile64x32(const float* __restrict__ src,
                                               int rowbase, int kbase,
                                               float* lds, int tid) {
  const int klane = tid & 7;
  const int row = tid >> 3;
#pragma unroll
  for (int p = 0; p < 2; ++p) {
    const int r = row + p * 32;
    const float4 v = *reinterpret_cast<const float4*>(
        src + (size_t)(rowbase + r) * 512 + kbase + 4 * klane);
    float* d = lds + r + (4 * klane) * LDSR;
    d[0 * LDSR] = v.x;
    d[1 * LDSR] = v.y;
    d[2 * LDSR] = v.z;
    d[3 * LDSR] = v.w;
  }
}

// K1: xp[bn,o] = sum_l x[bn,l]*W[o,l]; also emit bf16 copy xp16.
__global__ __launch_bounds__(256) void gemm_xw_kernel(const float* __restrict__ x,
                                                      const float* __restrict__ W,
                                                      float* __restrict__ xp,
                                                      unsigned short* __restrict__ xp16) {
  __shared__ float lA[TILE_K * LDSR];
  __shared__ float lB[TILE_K * LDSR];
  const int tid = threadIdx.x;
  const int tx = tid & 15, ty = tid >> 4;
  const int nbase = blockIdx.x * 64;
  const int obase = blockIdx.y * 64;
  float acc[4][4] = {};
  for (int kb = 0; kb < 512; kb += TILE_K) {
    load_tile64x32(x, nbase, kb, lA, tid);
    load_tile64x32(W, obase, kb, lB, tid);
    __syncthreads();
#pragma unroll
    for (int k = 0; k < TILE_K; ++k) {
      const float4 a4 = *reinterpret_cast<const float4*>(&lA[k * LDSR + 4 * ty]);
      const float4 b4 = *reinterpret_cast<const float4*>(&lB[k * LDSR + 4 * tx]);
      const float a[4] = {a4.x, a4.y, a4.z, a4.w};
      const float b[4] = {b4.x, b4.y, b4.z, b4.w};
#pragma unroll
      for (int i = 0; i < 4; ++i)
#pragma unroll
        for (int j = 0; j < 4; ++j) acc[i][j] = fmaf(a[i], b[j], acc[i][j]);
    }
    __syncthreads();
  }
#pragma unroll
  for (int i = 0; i < 4; ++i) {
    const size_t row = (size_t)(nbase + 4 * ty + i);
    const float4 v = {acc[i][0], acc[i][1], acc[i][2], acc[i][3]};
    *reinterpret_cast<float4*>(xp + row * 512 + obase + 4 * tx) = v;
    ushort4 u = {f2bf(acc[i][0]), f2bf(acc[i][1]), f2bf(acc[i][2]), f2bf(acc[i][3])};
    *reinterpret_cast<ushort4*>(xp16 + row * 512 + obase + 4 * tx) = u;
  }
}

__device__ __forceinline__ void ins2(float& v1, int& c1, float& v2, int& c2,
                                     float v, int c) {
  if (v < v1 || (v == v1 && c < c1)) {
    v2 = v1; c2 = c1; v1 = v; c1 = c;
  } else if (v < v2 || (v == v2 && c < c2)) {
    v2 = v; c2 = c;
  }
}

// K2: m97-structure score GEMM. Block = 256 thr (4 waves, 2x2), tile 128x128,
// BK=32, global_load_lds staging, fused top-2-per-64-col-slab epilogue.
__global__ __launch_bounds__(256) void score_kernel(const unsigned short* __restrict__ xp16,
                                                    float* __restrict__ cand) {
  __shared__ unsigned short lA[128 * 32];
  __shared__ unsigned short lB[128 * 32];
  const int tid = threadIdx.x;
  const int wid = tid >> 6, lane = tid & 63;
  const int lr = lane & 15, kg = lane >> 4;  // frag row / k-group
  const int b = blockIdx.x & 7;              // batch -> XCD pin
  const int rem = blockIdx.x >> 3;
  const int tn = rem & 15, tm = rem >> 4;
  const int nbase = tn * 128, mbase = tm * 128;
  const unsigned short* Xb = xp16 + (size_t)b * 2048 * 512;
  const int wr = wid >> 1, wc = wid & 1;     // wave -> 64x64 quadrant

  // staging: chunk c covers tile rows 64c..64c+63; thread t -> row 64c + t/4,
  // bf16 col (t&3)*8. LDS linear: c*2048 + tid*8 elems (wave-uniform base + lane*16B).
  const int srow = tid >> 2;
  const int scol = (tid & 3) * 8;
  const unsigned short* gA0 = Xb + (size_t)(nbase + srow) * 512 + scol;
  const unsigned short* gA1 = Xb + (size_t)(nbase + 64 + srow) * 512 + scol;
  const unsigned short* gB0 = Xb + (size_t)(mbase + srow) * 512 + scol;
  const unsigned short* gB1 = Xb + (size_t)(mbase + 64 + srow) * 512 + scol;

  f32x4 acc[4][4] = {};
  for (int kb = 0; kb < 512; kb += 32) {
    __syncthreads();  // previous K-step's ds_reads done before overwrite
    gload_lds16(gA0 + kb, lA + wid * 512);
    gload_lds16(gA1 + kb, lA + 2048 + wid * 512);
    gload_lds16(gB0 + kb, lB + wid * 512);
    gload_lds16(gB1 + kb, lB + 2048 + wid * 512);
    __syncthreads();  // compiler drains vmcnt(0) before barrier
    bf16x8 af[4], bfr[4];
#pragma unroll
    for (int i = 0; i < 4; ++i) {
      af[i]  = *reinterpret_cast<const bf16x8*>(lA + (wr * 64 + i * 16 + lr) * 32 + kg * 8);
      bfr[i] = *reinterpret_cast<const bf16x8*>(lB + (wc * 64 + i * 16 + lr) * 32 + kg * 8);
    }
#pragma unroll
    for (int i = 0; i < 4; ++i)
#pragma unroll
      for (int j = 0; j < 4; ++j)
        acc[i][j] = __builtin_amdgcn_mfma_f32_16x16x32_bf16(af[i], bfr[j], acc[i][j], 0, 0, 0);
  }

  // Epilogue: C frag layout col=lane&15, row=(lane>>4)*4+reg. Top-2 per row
  // over this wave's 64 cols (slab = tm*2 + wc).
#pragma unroll
  for (int i = 0; i < 4; ++i) {
#pragma unroll
    for (int r = 0; r < 4; ++r) {
      float v1 = FLT_MAX, v2 = FLT_MAX;
      int c1 = 0x7fffffff, c2 = 0x7fffffff;
#pragma unroll
      for (int j = 0; j < 4; ++j)
        ins2(v1, c1, v2, c2, acc[i][j][r], mbase + wc * 64 + j * 16 + lr);
#pragma unroll
      for (int off = 1; off < 16; off <<= 1) {
        const float ov1 = __shfl_xor(v1, off); const int oc1 = __shfl_xor(c1, off);
        const float ov2 = __shfl_xor(v2, off); const int oc2 = __shfl_xor(c2, off);
        ins2(v1, c1, v2, c2, ov1, oc1);
        ins2(v1, c1, v2, c2, ov2, oc2);
      }
      if (lr == 0) {
        const int n = nbase + wr * 64 + i * 16 + kg * 4 + r;
        const float4 outv = {v1, __int_as_float(c1), v2, __int_as_float(c2)};
        *reinterpret_cast<float4*>(cand + ((size_t)b * 2048 + n) * 512 + (tm * 2 + wc) * 4) = outv;
      }
    }
  }
}

// K3: per row: approx-top-8 of 64 cands -> exact f32 rescore -> argmin.
// Writes the full att row (no memset needed) and the h row.
__global__ __launch_bounds__(64) void finalize_kernel(const float* __restrict__ xp,
                                                      float* __restrict__ h,
                                                      float* __restrict__ att) {
  const int l = threadIdx.x;
  const int b = blockIdx.x & 7;  // batch -> XCD pin
  const int n = blockIdx.x >> 3;
  const size_t r = (size_t)b * 2048 + n;

  // own-row candidate scratch (written by K2 into h region)
  const float2 cc = reinterpret_cast<const float2*>(h + r * 512)[l];
  float cv = cc.x;
  int ci = __float_as_int(cc.y);

  int wsel[8];
#pragma unroll
  for (int t = 0; t < 8; ++t) {
    float mv = cv; int mi = ci;
#pragma unroll
    for (int off = 1; off < 64; off <<= 1) {
      const float ov = __shfl_xor(mv, off); const int oi = __shfl_xor(mi, off);
      if (ov < mv || (ov == mv && oi < mi)) { mv = ov; mi = oi; }
    }
    wsel[t] = mi;
    if (ci == mi) cv = FLT_MAX;  // invalidate winner (indices unique)
  }

  const float* xb = xp + (size_t)b * 2048 * 512;
  const float* xn = xb + (size_t)n * 512;
  const float4 q0 = reinterpret_cast<const float4*>(xn)[2 * l];
  const float4 q1 = reinterpret_cast<const float4*>(xn)[2 * l + 1];

  float bestv = FLT_MAX; int besti = 0x7fffffff;
#pragma unroll
  for (int t = 0; t < 8; ++t) {
    const float* xm = xb + (size_t)wsel[t] * 512;
    const float4 p0 = reinterpret_cast<const float4*>(xm)[2 * l];
    const float4 p1 = reinterpret_cast<const float4*>(xm)[2 * l + 1];
    float s = 0.f;
    s = fmaf(q0.x, p0.x, s); s = fmaf(q0.y, p0.y, s);
    s = fmaf(q0.z, p0.z, s); s = fmaf(q0.w, p0.w, s);
    s = fmaf(q1.x, p1.x, s); s = fmaf(q1.y, p1.y, s);
    s = fmaf(q1.z, p1.z, s); s = fmaf(q1.w, p1.w, s);
#pragma unroll
    for (int off = 1; off < 64; off <<= 1) s += __shfl_xor(s, off);
    if (s < bestv || (s == bestv && wsel[t] < besti)) { bestv = s; besti = wsel[t]; }
  }

  // h row = xp[b, besti, :]
  const float* xs = xb + (size_t)besti * 512;
  const float4 w0 = reinterpret_cast<const float4*>(xs)[2 * l];
  const float4 w1 = reinterpret_cast<const float4*>(xs)[2 * l + 1];
  float* hrow = h + r * 512;
  reinterpret_cast<float4*>(hrow)[2 * l] = w0;
  reinterpret_cast<float4*>(hrow)[2 * l + 1] = w1;

  // att row: zeros + one-hot at besti
  float* arow = att + r * 2048;
#pragma unroll
  for (int s = 0; s < 8; ++s) {
    const int cbase = s * 256 + l * 4;
    float4 v;
    v.x = (cbase + 0 == besti) ? 1.0f : 0.0f;
    v.y = (cbase + 1 == besti) ? 1.0f : 0.0f;
    v.z = (cbase + 2 == besti) ? 1.0f : 0.0f;
    v.w = (cbase + 3 == besti) ? 1.0f : 0.0f;
    reinterpret_cast<float4*>(arow)[s * 64 + l] = v;
  }
}

extern "C" void kernel_launch(void* const* d_in, const int* in_sizes, int n_in,
                              void* d_out, int out_size, void* d_ws, size_t ws_size,
                              hipStream_t stream) {
  const float* x = (const float*)d_in[0];  // [8,2048,512] f32
  const float* W = (const float*)d_in[1];  // [512,512] f32
  float* out = (float*)d_out;
  float* h = out;                              // [8,2048,512]
  float* att = out + (size_t)8 * 2048 * 512;   // [8,2048,2048]
  float* xp = (float*)d_ws;                    // 32 MB f32
  // bf16 xp in the LAST 16MB of the att region (dead before att is written)
  unsigned short* xp16 = (unsigned short*)(att + ((size_t)32 - 4) * 1024 * 1024);

  dim3 gridA(16384 / 64, 512 / 64);
  hipLaunchKernelGGL(gemm_xw_kernel, gridA, dim3(256), 0, stream, x, W, xp, xp16);

  // cand scratch = first 512B of each h row; grid = 8 batches x 16x16 tiles
  hipLaunchKernelGGL(score_kernel, dim3(8 * 16 * 16), dim3(256), 0, stream, xp16, h);

  hipLaunchKernelGGL(finalize_kernel, dim3(16384), dim3(64), 0, stream, xp, h, att);
}

// Round 4
// 215.355 us; speedup vs baseline: 3.8836x; 2.4802x over previous
//
#include <hip/hip_runtime.h>
#include <cfloat>

// kNNSelfAttention: softmax(mask*score) with multiplicative -1e19 mask is exactly
// one-hot at argmin_m score[n,m] (validated rounds 1-3, absmax 0.0).
//   K1: xp = x@W^T in exact f32 (feeds h and exact rescore) + bf16 copy
//   K2: bf16 MFMA score GEMM (128x128 tile, 2-phase dbuf global_load_lds) with
//       branchless u32-key top-2-per-64-col-slab epilogue -> 64 keys/row
//   K3: top-8 of keys via u32-min butterfly, exact f32 rescore, argmin ->
//       att row + h row
// Key = (sortable_f32 & 0xFFFFF800) | m_index(11b); min(key) = (min val, min idx).
// Scratch: keys live in each row's own h storage (no cross-block race);
// xp16 lives in the att-region tail (dead before att is written). ws = 32MB.

typedef short bf16x8 __attribute__((ext_vector_type(8)));
typedef float f32x4 __attribute__((ext_vector_type(4)));

#define TILE_K 32
#define LDSR 68  // 64 + 4 pad floats (K1 f32 tiles)

__device__ __forceinline__ unsigned short f2bf(float f) {
  unsigned int u = __float_as_uint(f);
  unsigned int r = (u + 0x7FFFu + ((u >> 16) & 1u)) >> 16;  // RNE
  return (unsigned short)r;
}

__device__ __forceinline__ void gload_lds16(const unsigned short* g, unsigned short* l) {
  __builtin_amdgcn_global_load_lds(
      (const __attribute__((address_space(1))) unsigned int*)g,
      (__attribute__((address_space(3))) unsigned int*)l, 16, 0, 0);
}

// sortable-f32 key: monotone map f32 -> u32, then pack 11-bit index in LSBs.
__device__ __forceinline__ unsigned int skey(float v, int m) {
  unsigned int u = __float_as_uint(v);
  u ^= ((unsigned int)((int)u >> 31)) | 0x80000000u;
  return (u & 0xFFFFF800u) | (unsigned int)m;
}

__device__ __forceinline__ void load_tile64x32(const float* __restrict__ src,
                                               int rowbase, int kbase,
                                               float* lds, int tid) {
  const int klane = tid & 7;
  const int row = tid >> 3;
#pragma unroll
  for (int p = 0; p < 2; ++p) {
    const int r = row + p * 32;
    const float4 v = *reinterpret_cast<const float4*>(
        src + (size_t)(rowbase + r) * 512 + kbase + 4 * klane);
    float* d = lds + r + (4 * klane) * LDSR;
    d[0 * LDSR] = v.x;
    d[1 * LDSR] = v.y;
    d[2 * LDSR] = v.z;
    d[3 * LDSR] = v.w;
  }
}

// K1: xp[bn,o] = sum_l x[bn,l]*W[o,l]; also emit bf16 copy xp16.
__global__ __launch_bounds__(256) void gemm_xw_kernel(const float* __restrict__ x,
                                                      const float* __restrict__ W,
                                                      float* __restrict__ xp,
                                                      unsigned short* __restrict__ xp16) {
  __shared__ float lA[TILE_K * LDSR];
  __shared__ float lB[TILE_K * LDSR];
  const int tid = threadIdx.x;
  const int tx = tid & 15, ty = tid >> 4;
  const int nbase = blockIdx.x * 64;
  const int obase = blockIdx.y * 64;
  float acc[4][4] = {};
  for (int kb = 0; kb < 512; kb += TILE_K) {
    load_tile64x32(x, nbase, kb, lA, tid);
    load_tile64x32(W, obase, kb, lB, tid);
    __syncthreads();
#pragma unroll
    for (int k = 0; k < TILE_K; ++k) {
      const float4 a4 = *reinterpret_cast<const float4*>(&lA[k * LDSR + 4 * ty]);
      const float4 b4 = *reinterpret_cast<const float4*>(&lB[k * LDSR + 4 * tx]);
      const float a[4] = {a4.x, a4.y, a4.z, a4.w};
      const float b[4] = {b4.x, b4.y, b4.z, b4.w};
#pragma unroll
      for (int i = 0; i < 4; ++i)
#pragma unroll
        for (int j = 0; j < 4; ++j) acc[i][j] = fmaf(a[i], b[j], acc[i][j]);
    }
    __syncthreads();
  }
#pragma unroll
  for (int i = 0; i < 4; ++i) {
    const size_t row = (size_t)(nbase + 4 * ty + i);
    const float4 v = {acc[i][0], acc[i][1], acc[i][2], acc[i][3]};
    *reinterpret_cast<float4*>(xp + row * 512 + obase + 4 * tx) = v;
    ushort4 u = {f2bf(acc[i][0]), f2bf(acc[i][1]), f2bf(acc[i][2]), f2bf(acc[i][3])};
    *reinterpret_cast<ushort4*>(xp16 + row * 512 + obase + 4 * tx) = u;
  }
}

// K2: 128x128 tile, 4 waves (2x2), BK=32, 2-phase dbuf staging, u32-key epilogue.
__global__ __launch_bounds__(256) void score_kernel(const unsigned short* __restrict__ xp16,
                                                    unsigned int* __restrict__ cand) {
  __shared__ unsigned short lA[2][128 * 32];
  __shared__ unsigned short lB[2][128 * 32];
  const int tid = threadIdx.x;
  const int wid = tid >> 6, lane = tid & 63;
  const int lr = lane & 15, kg = lane >> 4;  // frag row / k-group
  const int b = blockIdx.x & 7;              // batch -> XCD pin
  const int rem = blockIdx.x >> 3;
  const int tn = rem & 15, tm = rem >> 4;
  const int nbase = tn * 128, mbase = tm * 128;
  const unsigned short* Xb = xp16 + (size_t)b * 2048 * 512;
  const int wr = wid >> 1, wc = wid & 1;     // wave -> 64x64 quadrant

  // staging map: thread t -> row t>>2 (+64 for second call), bf16 col (t&3)*8.
  // LDS dest is linear (wave-uniform base + lane*16B) matching [row][32] layout.
  const int srow = tid >> 2;
  const int scol = (tid & 3) * 8;
  const unsigned short* gA0 = Xb + (size_t)(nbase + srow) * 512 + scol;
  const unsigned short* gA1 = Xb + (size_t)(nbase + 64 + srow) * 512 + scol;
  const unsigned short* gB0 = Xb + (size_t)(mbase + srow) * 512 + scol;
  const unsigned short* gB1 = Xb + (size_t)(mbase + 64 + srow) * 512 + scol;

  f32x4 acc[4][4] = {};

#define STAGE(KB, BUF)                                    \
  do {                                                    \
    gload_lds16(gA0 + (KB), &lA[BUF][wid * 512]);         \
    gload_lds16(gA1 + (KB), &lA[BUF][2048 + wid * 512]);  \
    gload_lds16(gB0 + (KB), &lB[BUF][wid * 512]);         \
    gload_lds16(gB1 + (KB), &lB[BUF][2048 + wid * 512]);  \
  } while (0)

#define COMPUTE(BUF)                                                                   \
  do {                                                                                 \
    bf16x8 af[4], bfr[4];                                                              \
    _Pragma("unroll") for (int i2 = 0; i2 < 4; ++i2) {                                 \
      af[i2] = *reinterpret_cast<const bf16x8*>(&lA[BUF][(wr * 64 + i2 * 16 + lr) * 32 + kg * 8]); \
      bfr[i2] = *reinterpret_cast<const bf16x8*>(&lB[BUF][(wc * 64 + i2 * 16 + lr) * 32 + kg * 8]); \
    }                                                                                  \
    _Pragma("unroll") for (int i2 = 0; i2 < 4; ++i2)                                   \
        _Pragma("unroll") for (int j2 = 0; j2 < 4; ++j2)                               \
            acc[i2][j2] =                                                              \
                __builtin_amdgcn_mfma_f32_16x16x32_bf16(af[i2], bfr[j2], acc[i2][j2], 0, 0, 0); \
  } while (0)

  STAGE(0, 0);
  __syncthreads();  // drain prologue stage
  for (int t = 0; t < 15; ++t) {
    STAGE((t + 1) * 32, (t & 1) ^ 1);  // issue next tile first (overlaps MFMA)
    COMPUTE(t & 1);
    __syncthreads();  // drains vmcnt(0): next tile staged; cur reads done
  }
  COMPUTE(1);

  // Epilogue: C frag layout col=lane&15, row=(lane>>4)*4+reg (per 16x16 frag).
  // Branchless top-2 per wave's 64-col slab via sortable u32 keys.
  const int mcol = mbase + wc * 64 + lr;
#pragma unroll
  for (int i = 0; i < 4; ++i) {
#pragma unroll
    for (int r = 0; r < 4; ++r) {
      const unsigned int x0 = skey(acc[i][0][r], mcol + 0);
      const unsigned int x1 = skey(acc[i][1][r], mcol + 16);
      const unsigned int x2 = skey(acc[i][2][r], mcol + 32);
      const unsigned int x3 = skey(acc[i][3][r], mcol + 48);
      const unsigned int lo01 = min(x0, x1), hi01 = max(x0, x1);
      const unsigned int lo23 = min(x2, x3), hi23 = max(x2, x3);
      unsigned int k1 = min(lo01, lo23);
      unsigned int k2 = min(max(lo01, lo23), min(hi01, hi23));
#pragma unroll
      for (int off = 1; off < 16; off <<= 1) {
        const unsigned int o1 = (unsigned int)__shfl_xor((int)k1, off);
        const unsigned int o2 = (unsigned int)__shfl_xor((int)k2, off);
        const unsigned int nk1 = min(k1, o1);
        const unsigned int nk2 = min(max(k1, o1), min(k2, o2));
        k1 = nk1;
        k2 = nk2;
      }
      if (lr == 0) {
        const int n = nbase + wr * 64 + i * 16 + kg * 4 + r;
        const uint2 kv = {k1, k2};
        *reinterpret_cast<uint2*>(cand + ((size_t)b * 2048 + n) * 512 + (tm * 2 + wc) * 2) = kv;
      }
    }
  }
#undef STAGE
#undef COMPUTE
}

// K3: per row: top-8 of 64 keys (u32-min butterfly) -> exact f32 rescore ->
// argmin -> write full att row (no memset needed) + h row.
__global__ __launch_bounds__(64) void finalize_kernel(const float* __restrict__ xp,
                                                      float* __restrict__ h,
                                                      float* __restrict__ att) {
  const int l = threadIdx.x;
  const int b = blockIdx.x & 7;  // batch -> XCD pin
  const int n = blockIdx.x >> 3;
  const size_t r = (size_t)b * 2048 + n;

  // own-row key scratch (written by K2 into h region); keys unique per row.
  unsigned int key = reinterpret_cast<const unsigned int*>(h + r * 512)[l];
  int wsel[8];
#pragma unroll
  for (int t = 0; t < 8; ++t) {
    unsigned int m = key;
#pragma unroll
    for (int off = 1; off < 64; off <<= 1)
      m = min(m, (unsigned int)__shfl_xor((int)m, off));
    wsel[t] = (int)(m & 0x7FFu);
    if (key == m) key = 0xFFFFFFFFu;  // invalidate winner
  }

  const float* xb = xp + (size_t)b * 2048 * 512;
  const float* xn = xb + (size_t)n * 512;
  const float4 q0 = reinterpret_cast<const float4*>(xn)[2 * l];
  const float4 q1 = reinterpret_cast<const float4*>(xn)[2 * l + 1];

  float bestv = FLT_MAX;
  int besti = 0x7fffffff;
#pragma unroll
  for (int t = 0; t < 8; ++t) {
    const float* xm = xb + (size_t)wsel[t] * 512;
    const float4 p0 = reinterpret_cast<const float4*>(xm)[2 * l];
    const float4 p1 = reinterpret_cast<const float4*>(xm)[2 * l + 1];
    float s = 0.f;
    s = fmaf(q0.x, p0.x, s); s = fmaf(q0.y, p0.y, s);
    s = fmaf(q0.z, p0.z, s); s = fmaf(q0.w, p0.w, s);
    s = fmaf(q1.x, p1.x, s); s = fmaf(q1.y, p1.y, s);
    s = fmaf(q1.z, p1.z, s); s = fmaf(q1.w, p1.w, s);
#pragma unroll
    for (int off = 1; off < 64; off <<= 1) s += __shfl_xor(s, off);
    if (s < bestv || (s == bestv && wsel[t] < besti)) { bestv = s; besti = wsel[t]; }
  }

  // h row = xp[b, besti, :]
  const float* xs = xb + (size_t)besti * 512;
  const float4 w0 = reinterpret_cast<const float4*>(xs)[2 * l];
  const float4 w1 = reinterpret_cast<const float4*>(xs)[2 * l + 1];
  float* hrow = h + r * 512;
  reinterpret_cast<float4*>(hrow)[2 * l] = w0;
  reinterpret_cast<float4*>(hrow)[2 * l + 1] = w1;

  // att row: zeros + one-hot at besti
  float* arow = att + r * 2048;
#pragma unroll
  for (int s = 0; s < 8; ++s) {
    const int cbase = s * 256 + l * 4;
    float4 v;
    v.x = (cbase + 0 == besti) ? 1.0f : 0.0f;
    v.y = (cbase + 1 == besti) ? 1.0f : 0.0f;
    v.z = (cbase + 2 == besti) ? 1.0f : 0.0f;
    v.w = (cbase + 3 == besti) ? 1.0f : 0.0f;
    reinterpret_cast<float4*>(arow)[s * 64 + l] = v;
  }
}

extern "C" void kernel_launch(void* const* d_in, const int* in_sizes, int n_in,
                              void* d_out, int out_size, void* d_ws, size_t ws_size,
                              hipStream_t stream) {
  const float* x = (const float*)d_in[0];  // [8,2048,512] f32
  const float* W = (const float*)d_in[1];  // [512,512] f32
  float* out = (float*)d_out;
  float* h = out;                              // [8,2048,512]
  float* att = out + (size_t)8 * 2048 * 512;   // [8,2048,2048]
  float* xp = (float*)d_ws;                    // 32 MB f32
  // bf16 xp in the LAST 16MB of the att region (dead before att is written)
  unsigned short* xp16 = (unsigned short*)(att + ((size_t)32 - 4) * 1024 * 1024);

  dim3 gridA(16384 / 64, 512 / 64);
  hipLaunchKernelGGL(gemm_xw_kernel, gridA, dim3(256), 0, stream, x, W, xp, xp16);

  // key scratch = first 256B of each h row; grid = 8 batches x 16x16 tiles
  hipLaunchKernelGGL(score_kernel, dim3(8 * 16 * 16), dim3(256), 0, stream, xp16,
                     (unsigned int*)h);

  hipLaunchKernelGGL(finalize_kernel, dim3(16384), dim3(64), 0, stream, xp, h, att);
}

// Round 5
// 206.820 us; speedup vs baseline: 4.0438x; 1.0413x over previous
//
#include <hip/hip_runtime.h>
#include <cfloat>

// kNNSelfAttention: softmax(mask*score) with multiplicative -1e19 mask is exactly
// one-hot at argmin_m score[n,m] (validated rounds 1-4, absmax 0.0).
//   K1: xp = x@W^T in exact f32 (feeds h and exact rescore) + bf16 copy.
//       128x64 tile, 8x4 acc/thread, dbuf LDS, async-split staging. The
//       accumulation order (k ascending, fmaf) is IDENTICAL to prior rounds,
//       so xp/xp16 are bitwise unchanged -> zero new correctness risk.
//   K2: bf16 MFMA score GEMM (128x128 tile, 2-phase dbuf global_load_lds) with
//       branchless u32-key top-2-per-64-col-slab epilogue -> 64 keys/row
//   K3: top-8 of keys via u32-min butterfly, exact f32 rescore, argmin ->
//       att row + h row
// Key = (sortable_f32 & 0xFFFFF800) | m_index(11b); min(key) = (min val, min idx).
// Scratch: keys live in each row's own h storage (no cross-block race);
// xp16 lives in the att-region tail (dead before att is written). ws = 32MB.

typedef short bf16x8 __attribute__((ext_vector_type(8)));
typedef float f32x4 __attribute__((ext_vector_type(4)));

#define K1_LDSA 132  // 128 + 4 pad (528 B, 16B-aligned; staging writes 4-way not 8)
#define K1_LDSB 68   // 64 + 4 pad (272 B, 16B-aligned)

__device__ __forceinline__ unsigned short f2bf(float f) {
  unsigned int u = __float_as_uint(f);
  unsigned int r = (u + 0x7FFFu + ((u >> 16) & 1u)) >> 16;  // RNE
  return (unsigned short)r;
}

__device__ __forceinline__ void gload_lds16(const unsigned short* g, unsigned short* l) {
  __builtin_amdgcn_global_load_lds(
      (const __attribute__((address_space(1))) unsigned int*)g,
      (__attribute__((address_space(3))) unsigned int*)l, 16, 0, 0);
}

// sortable-f32 key: monotone map f32 -> u32, then pack 11-bit index in LSBs.
__device__ __forceinline__ unsigned int skey(float v, int m) {
  unsigned int u = __float_as_uint(v);
  u ^= ((unsigned int)((int)u >> 31)) | 0x80000000u;
  return (u & 0xFFFFF800u) | (unsigned int)m;
}

// K1: xp[bn,o] = sum_l x[bn,l]*W[o,l]; also emit bf16 copy xp16.
// 128x64 tile, 256 thr, 8x4 acc. K-order per element unchanged (bitwise-stable).
__global__ __launch_bounds__(256) void gemm_xw_kernel(const float* __restrict__ x,
                                                      const float* __restrict__ W,
                                                      float* __restrict__ xp,
                                                      unsigned short* __restrict__ xp16) {
  __shared__ float lA[2][32 * K1_LDSA];
  __shared__ float lB[2][32 * K1_LDSB];
  const int tid = threadIdx.x;
  const int tx = tid & 15, ty = tid >> 4;
  const int nbase = blockIdx.x * 128;
  const int obase = blockIdx.y * 64;
  const int kc4 = (tid & 7) * 4;  // k-chunk base 0..28
  const int rr = tid >> 3;        // 0..31

  float acc[8][4] = {};
  float4 va[4], vb[2];

#define K1_LOAD(KB)                                                                   \
  do {                                                                                \
    _Pragma("unroll") for (int p = 0; p < 4; ++p)                                     \
        va[p] = *reinterpret_cast<const float4*>(                                     \
            x + (size_t)(nbase + rr + 32 * p) * 512 + (KB) + kc4);                    \
    _Pragma("unroll") for (int p = 0; p < 2; ++p)                                     \
        vb[p] = *reinterpret_cast<const float4*>(                                     \
            W + (size_t)(obase + rr + 32 * p) * 512 + (KB) + kc4);                    \
  } while (0)

#define K1_WRITE(BUF)                                                                 \
  do {                                                                                \
    _Pragma("unroll") for (int p = 0; p < 4; ++p) {                                   \
      float* d = &lA[BUF][kc4 * K1_LDSA + rr + 32 * p];                               \
      d[0] = va[p].x; d[K1_LDSA] = va[p].y;                                           \
      d[2 * K1_LDSA] = va[p].z; d[3 * K1_LDSA] = va[p].w;                             \
    }                                                                                 \
    _Pragma("unroll") for (int p = 0; p < 2; ++p) {                                   \
      float* d = &lB[BUF][kc4 * K1_LDSB + rr + 32 * p];                               \
      d[0] = vb[p].x; d[K1_LDSB] = vb[p].y;                                           \
      d[2 * K1_LDSB] = vb[p].z; d[3 * K1_LDSB] = vb[p].w;                             \
    }                                                                                 \
  } while (0)

#define K1_COMPUTE(BUF)                                                               \
  do {                                                                                \
    _Pragma("unroll") for (int k = 0; k < 32; ++k) {                                  \
      const float4 a0 = *reinterpret_cast<const float4*>(&lA[BUF][k * K1_LDSA + 4 * ty]);      \
      const float4 a1 = *reinterpret_cast<const float4*>(&lA[BUF][k * K1_LDSA + 64 + 4 * ty]); \
      const float4 b0 = *reinterpret_cast<const float4*>(&lB[BUF][k * K1_LDSB + 4 * tx]);      \
      const float a[8] = {a0.x, a0.y, a0.z, a0.w, a1.x, a1.y, a1.z, a1.w};            \
      const float b[4] = {b0.x, b0.y, b0.z, b0.w};                                    \
      _Pragma("unroll") for (int i = 0; i < 8; ++i)                                   \
          _Pragma("unroll") for (int j = 0; j < 4; ++j)                               \
              acc[i][j] = fmaf(a[i], b[j], acc[i][j]);                                \
    }                                                                                 \
  } while (0)

  K1_LOAD(0);
  K1_WRITE(0);
  __syncthreads();
  for (int t = 0; t < 15; ++t) {
    K1_LOAD((t + 1) * 32);   // issue next tile's global loads
    K1_COMPUTE(t & 1);       // ~2048 cyc/wave hides the load latency
    K1_WRITE((t & 1) ^ 1);   // vmcnt drain lands here, post-compute
    __syncthreads();
  }
  K1_COMPUTE(1);

#pragma unroll
  for (int i = 0; i < 8; ++i) {
    const size_t row = (size_t)(nbase + 4 * ty + (i & 3) + 64 * (i >> 2));
    const float4 v = {acc[i][0], acc[i][1], acc[i][2], acc[i][3]};
    *reinterpret_cast<float4*>(xp + row * 512 + obase + 4 * tx) = v;
    ushort4 u = {f2bf(acc[i][0]), f2bf(acc[i][1]), f2bf(acc[i][2]), f2bf(acc[i][3])};
    *reinterpret_cast<ushort4*>(xp16 + row * 512 + obase + 4 * tx) = u;
  }
#undef K1_LOAD
#undef K1_WRITE
#undef K1_COMPUTE
}

// K2: 128x128 tile, 4 waves (2x2), BK=32, 2-phase dbuf staging, u32-key epilogue.
__global__ __launch_bounds__(256) void score_kernel(const unsigned short* __restrict__ xp16,
                                                    unsigned int* __restrict__ cand) {
  __shared__ unsigned short lA[2][128 * 32];
  __shared__ unsigned short lB[2][128 * 32];
  const int tid = threadIdx.x;
  const int wid = tid >> 6, lane = tid & 63;
  const int lr = lane & 15, kg = lane >> 4;  // frag row / k-group
  const int b = blockIdx.x & 7;              // batch -> XCD pin
  const int rem = blockIdx.x >> 3;
  const int tn = rem & 15, tm = rem >> 4;
  const int nbase = tn * 128, mbase = tm * 128;
  const unsigned short* Xb = xp16 + (size_t)b * 2048 * 512;
  const int wr = wid >> 1, wc = wid & 1;     // wave -> 64x64 quadrant

  // staging map: thread t -> row t>>2 (+64 for second call), bf16 col (t&3)*8.
  // LDS dest is linear (wave-uniform base + lane*16B) matching [row][32] layout.
  const int srow = tid >> 2;
  const int scol = (tid & 3) * 8;
  const unsigned short* gA0 = Xb + (size_t)(nbase + srow) * 512 + scol;
  const unsigned short* gA1 = Xb + (size_t)(nbase + 64 + srow) * 512 + scol;
  const unsigned short* gB0 = Xb + (size_t)(mbase + srow) * 512 + scol;
  const unsigned short* gB1 = Xb + (size_t)(mbase + 64 + srow) * 512 + scol;

  f32x4 acc[4][4] = {};

#define STAGE(KB, BUF)                                    \
  do {                                                    \
    gload_lds16(gA0 + (KB), &lA[BUF][wid * 512]);         \
    gload_lds16(gA1 + (KB), &lA[BUF][2048 + wid * 512]);  \
    gload_lds16(gB0 + (KB), &lB[BUF][wid * 512]);         \
    gload_lds16(gB1 + (KB), &lB[BUF][2048 + wid * 512]);  \
  } while (0)

#define COMPUTE(BUF)                                                                   \
  do {                                                                                 \
    bf16x8 af[4], bfr[4];                                                              \
    _Pragma("unroll") for (int i2 = 0; i2 < 4; ++i2) {                                 \
      af[i2] = *reinterpret_cast<const bf16x8*>(&lA[BUF][(wr * 64 + i2 * 16 + lr) * 32 + kg * 8]); \
      bfr[i2] = *reinterpret_cast<const bf16x8*>(&lB[BUF][(wc * 64 + i2 * 16 + lr) * 32 + kg * 8]); \
    }                                                                                  \
    _Pragma("unroll") for (int i2 = 0; i2 < 4; ++i2)                                   \
        _Pragma("unroll") for (int j2 = 0; j2 < 4; ++j2)                               \
            acc[i2][j2] =                                                              \
                __builtin_amdgcn_mfma_f32_16x16x32_bf16(af[i2], bfr[j2], acc[i2][j2], 0, 0, 0); \
  } while (0)

  STAGE(0, 0);
  __syncthreads();  // drain prologue stage
  for (int t = 0; t < 15; ++t) {
    STAGE((t + 1) * 32, (t & 1) ^ 1);  // issue next tile first (overlaps MFMA)
    COMPUTE(t & 1);
    __syncthreads();  // drains vmcnt(0): next tile staged; cur reads done
  }
  COMPUTE(1);

  // Epilogue: C frag layout col=lane&15, row=(lane>>4)*4+reg (per 16x16 frag).
  // Branchless top-2 per wave's 64-col slab via sortable u32 keys.
  const int mcol = mbase + wc * 64 + lr;
#pragma unroll
  for (int i = 0; i < 4; ++i) {
#pragma unroll
    for (int r = 0; r < 4; ++r) {
      const unsigned int x0 = skey(acc[i][0][r], mcol + 0);
      const unsigned int x1 = skey(acc[i][1][r], mcol + 16);
      const unsigned int x2 = skey(acc[i][2][r], mcol + 32);
      const unsigned int x3 = skey(acc[i][3][r], mcol + 48);
      const unsigned int lo01 = min(x0, x1), hi01 = max(x0, x1);
      const unsigned int lo23 = min(x2, x3), hi23 = max(x2, x3);
      unsigned int k1 = min(lo01, lo23);
      unsigned int k2 = min(max(lo01, lo23), min(hi01, hi23));
#pragma unroll
      for (int off = 1; off < 16; off <<= 1) {
        const unsigned int o1 = (unsigned int)__shfl_xor((int)k1, off);
        const unsigned int o2 = (unsigned int)__shfl_xor((int)k2, off);
        const unsigned int nk1 = min(k1, o1);
        const unsigned int nk2 = min(max(k1, o1), min(k2, o2));
        k1 = nk1;
        k2 = nk2;
      }
      if (lr == 0) {
        const int n = nbase + wr * 64 + i * 16 + kg * 4 + r;
        const uint2 kv = {k1, k2};
        *reinterpret_cast<uint2*>(cand + ((size_t)b * 2048 + n) * 512 + (tm * 2 + wc) * 2) = kv;
      }
    }
  }
#undef STAGE
#undef COMPUTE
}

// K3: per row: top-8 of 64 keys (u32-min butterfly) -> exact f32 rescore ->
// argmin -> write full att row (no memset needed) + h row.
__global__ __launch_bounds__(64) void finalize_kernel(const float* __restrict__ xp,
                                                      float* __restrict__ h,
                                                      float* __restrict__ att) {
  const int l = threadIdx.x;
  const int b = blockIdx.x & 7;  // batch -> XCD pin
  const int n = blockIdx.x >> 3;
  const size_t r = (size_t)b * 2048 + n;

  // own-row key scratch (written by K2 into h region); keys unique per row.
  unsigned int key = reinterpret_cast<const unsigned int*>(h + r * 512)[l];
  int wsel[8];
#pragma unroll
  for (int t = 0; t < 8; ++t) {
    unsigned int m = key;
#pragma unroll
    for (int off = 1; off < 64; off <<= 1)
      m = min(m, (unsigned int)__shfl_xor((int)m, off));
    wsel[t] = (int)(m & 0x7FFu);
    if (key == m) key = 0xFFFFFFFFu;  // invalidate winner
  }

  const float* xb = xp + (size_t)b * 2048 * 512;
  const float* xn = xb + (size_t)n * 512;
  const float4 q0 = reinterpret_cast<const float4*>(xn)[2 * l];
  const float4 q1 = reinterpret_cast<const float4*>(xn)[2 * l + 1];

  float bestv = FLT_MAX;
  int besti = 0x7fffffff;
#pragma unroll
  for (int t = 0; t < 8; ++t) {
    const float* xm = xb + (size_t)wsel[t] * 512;
    const float4 p0 = reinterpret_cast<const float4*>(xm)[2 * l];
    const float4 p1 = reinterpret_cast<const float4*>(xm)[2 * l + 1];
    float s = 0.f;
    s = fmaf(q0.x, p0.x, s); s = fmaf(q0.y, p0.y, s);
    s = fmaf(q0.z, p0.z, s); s = fmaf(q0.w, p0.w, s);
    s = fmaf(q1.x, p1.x, s); s = fmaf(q1.y, p1.y, s);
    s = fmaf(q1.z, p1.z, s); s = fmaf(q1.w, p1.w, s);
#pragma unroll
    for (int off = 1; off < 64; off <<= 1) s += __shfl_xor(s, off);
    if (s < bestv || (s == bestv && wsel[t] < besti)) { bestv = s; besti = wsel[t]; }
  }

  // h row = xp[b, besti, :]
  const float* xs = xb + (size_t)besti * 512;
  const float4 w0 = reinterpret_cast<const float4*>(xs)[2 * l];
  const float4 w1 = reinterpret_cast<const float4*>(xs)[2 * l + 1];
  float* hrow = h + r * 512;
  reinterpret_cast<float4*>(hrow)[2 * l] = w0;
  reinterpret_cast<float4*>(hrow)[2 * l + 1] = w1;

  // att row: zeros + one-hot at besti
  float* arow = att + r * 2048;
#pragma unroll
  for (int s = 0; s < 8; ++s) {
    const int cbase = s * 256 + l * 4;
    float4 v;
    v.x = (cbase + 0 == besti) ? 1.0f : 0.0f;
    v.y = (cbase + 1 == besti) ? 1.0f : 0.0f;
    v.z = (cbase + 2 == besti) ? 1.0f : 0.0f;
    v.w = (cbase + 3 == besti) ? 1.0f : 0.0f;
    reinterpret_cast<float4*>(arow)[s * 64 + l] = v;
  }
}

extern "C" void kernel_launch(void* const* d_in, const int* in_sizes, int n_in,
                              void* d_out, int out_size, void* d_ws, size_t ws_size,
                              hipStream_t stream) {
  const float* x = (const float*)d_in[0];  // [8,2048,512] f32
  const float* W = (const float*)d_in[1];  // [512,512] f32
  float* out = (float*)d_out;
  float* h = out;                              // [8,2048,512]
  float* att = out + (size_t)8 * 2048 * 512;   // [8,2048,2048]
  float* xp = (float*)d_ws;                    // 32 MB f32
  // bf16 xp in the LAST 16MB of the att region (dead before att is written)
  unsigned short* xp16 = (unsigned short*)(att + ((size_t)32 - 4) * 1024 * 1024);

  dim3 gridA(16384 / 128, 512 / 64);
  hipLaunchKernelGGL(gemm_xw_kernel, gridA, dim3(256), 0, stream, x, W, xp, xp16);

  // key scratch = first 256B of each h row; grid = 8 batches x 16x16 tiles
  hipLaunchKernelGGL(score_kernel, dim3(8 * 16 * 16), dim3(256), 0, stream, xp16,
                     (unsigned int*)h);

  hipLaunchKernelGGL(finalize_kernel, dim3(16384), dim3(64), 0, stream, xp, h, att);
}

// Round 6
// 204.591 us; speedup vs baseline: 4.0879x; 1.0109x over previous
//
#include <hip/hip_runtime.h>
#include <cfloat>

// kNNSelfAttention: softmax(mask*score) with multiplicative -1e19 mask is exactly
// one-hot at argmin_m score[n,m] (validated rounds 1-5, absmax 0.0).
//   K1: xp = x@W^T in exact f32 (feeds h and exact rescore) + bf16 copy.
//       128x64 tile, 8x4 acc/thread, dbuf LDS, XOR-swizzled stores (2-way max),
//       f32x2-packed FMA (v_pk_fma_f32). Per-element accumulation order
//       (k ascending, fma) is IDENTICAL to rounds 1-5 -> xp bitwise unchanged.
//   K2: bf16 MFMA score GEMM (128x128 tile, 2-phase dbuf global_load_lds) with
//       branchless u32-key top-2-per-64-col-slab epilogue -> 64 keys/row
//   K3: top-8 of keys via u32-min butterfly, exact f32 rescore, argmin ->
//       att row + h row
// Key = (sortable_f32 & 0xFFFFF800) | m_index(11b); min(key) = (min val, min idx).
// Scratch: keys live in each row's own h storage (no cross-block race);
// xp16 lives in the att-region tail (dead before att is written). ws = 32MB.

typedef short bf16x8 __attribute__((ext_vector_type(8)));
typedef float f32x4 __attribute__((ext_vector_type(4)));
typedef float f32x2 __attribute__((ext_vector_type(2)));

#define K1_LDA 128  // floats per k-row (A), no pad: swizzle handles banks
#define K1_LDB 64

__device__ __forceinline__ unsigned short f2bf(float f) {
  unsigned int u = __float_as_uint(f);
  unsigned int r = (u + 0x7FFFu + ((u >> 16) & 1u)) >> 16;  // RNE
  return (unsigned short)r;
}

__device__ __forceinline__ void gload_lds16(const unsigned short* g, unsigned short* l) {
  __builtin_amdgcn_global_load_lds(
      (const __attribute__((address_space(1))) unsigned int*)g,
      (__attribute__((address_space(3))) unsigned int*)l, 16, 0, 0);
}

// sortable-f32 key: monotone map f32 -> u32, then pack 11-bit index in LSBs.
__device__ __forceinline__ unsigned int skey(float v, int m) {
  unsigned int u = __float_as_uint(v);
  u ^= ((unsigned int)((int)u >> 31)) | 0x80000000u;
  return (u & 0xFFFFF800u) | (unsigned int)m;
}

__device__ __forceinline__ f32x2 pkfma(f32x2 a, f32x2 b, f32x2 c) {
#if __has_builtin(__builtin_elementwise_fma)
  return __builtin_elementwise_fma(a, b, c);  // llvm.fma.v2f32 -> v_pk_fma_f32
#else
  f32x2 r;
  r.x = fmaf(a.x, b.x, c.x);
  r.y = fmaf(a.y, b.y, c.y);
  return r;
#endif
}

// K1: xp[bn,o] = sum_l x[bn,l]*W[o,l]; also emit bf16 copy xp16.
// 128x64 tile, 256 thr, 8x4 acc (as 8x2 f32x2). Bitwise-stable k-order.
// LDS swizzle: element (k, r) stored at k*LD + (r ^ (((k>>2)&3)<<3)).
// Writer: k>>2 == tid&7 for its 4 k's -> swizzle = (tid&3)<<3, uniform/thread.
// Write banks: (r ^ s) mod 32 over lanes = exactly 2 lanes/bank (free).
// Reads: float4 at (4*t ^ sk) stays contiguous (XOR touches bits 3-4 only).
__global__ __launch_bounds__(256) void gemm_xw_kernel(const float* __restrict__ x,
                                                      const float* __restrict__ W,
                                                      float* __restrict__ xp,
                                                      unsigned short* __restrict__ xp16) {
  __shared__ float lA[2][32 * K1_LDA];
  __shared__ float lB[2][32 * K1_LDB];
  const int tid = threadIdx.x;
  const int tx = tid & 15, ty = tid >> 4;
  const int nbase = blockIdx.x * 128;
  const int obase = blockIdx.y * 64;
  const int kc4 = (tid & 7) * 4;        // this thread's k-chunk base (0..28)
  const int rr = tid >> 3;              // 0..31
  const int sw = (tid & 3) << 3;        // write swizzle = ((k>>2)&3)<<3 for its k's
  const int rsw = rr ^ sw;              // swizzled row base

  f32x2 acc[8][2] = {};
  float4 va[4], vb[2];

#define K1_LOAD(KB)                                                                   \
  do {                                                                                \
    _Pragma("unroll") for (int p = 0; p < 4; ++p)                                     \
        va[p] = *reinterpret_cast<const float4*>(                                     \
            x + (size_t)(nbase + rr + 32 * p) * 512 + (KB) + kc4);                    \
    _Pragma("unroll") for (int p = 0; p < 2; ++p)                                     \
        vb[p] = *reinterpret_cast<const float4*>(                                     \
            W + (size_t)(obase + rr + 32 * p) * 512 + (KB) + kc4);                    \
  } while (0)

#define K1_WRITE(BUF)                                                                 \
  do {                                                                                \
    _Pragma("unroll") for (int p = 0; p < 4; ++p) {                                   \
      float* d = &lA[BUF][kc4 * K1_LDA + rsw + 32 * p];                               \
      d[0] = va[p].x; d[K1_LDA] = va[p].y;                                            \
      d[2 * K1_LDA] = va[p].z; d[3 * K1_LDA] = va[p].w;                               \
    }                                                                                 \
    _Pragma("unroll") for (int p = 0; p < 2; ++p) {                                   \
      float* d = &lB[BUF][kc4 * K1_LDB + rsw + 32 * p];                               \
      d[0] = vb[p].x; d[K1_LDB] = vb[p].y;                                            \
      d[2 * K1_LDB] = vb[p].z; d[3 * K1_LDB] = vb[p].w;                               \
    }                                                                                 \
  } while (0)

#define K1_COMPUTE(BUF)                                                               \
  do {                                                                                \
    _Pragma("unroll") for (int k = 0; k < 32; ++k) {                                  \
      const int sk = ((k >> 2) & 3) << 3;                                             \
      const float4 a0 = *reinterpret_cast<const float4*>(                             \
          &lA[BUF][k * K1_LDA + ((4 * ty) ^ sk)]);                                    \
      const float4 a1 = *reinterpret_cast<const float4*>(                             \
          &lA[BUF][k * K1_LDA + 64 + ((4 * ty) ^ sk)]);                               \
      const float4 b0 = *reinterpret_cast<const float4*>(                             \
          &lB[BUF][k * K1_LDB + ((4 * tx) ^ sk)]);                                    \
      const f32x2 b01 = {b0.x, b0.y};                                                 \
      const f32x2 b23 = {b0.z, b0.w};                                                 \
      const float a[8] = {a0.x, a0.y, a0.z, a0.w, a1.x, a1.y, a1.z, a1.w};            \
      _Pragma("unroll") for (int i = 0; i < 8; ++i) {                                 \
        const f32x2 av = {a[i], a[i]};                                                \
        acc[i][0] = pkfma(av, b01, acc[i][0]);                                        \
        acc[i][1] = pkfma(av, b23, acc[i][1]);                                        \
      }                                                                               \
    }                                                                                 \
  } while (0)

  K1_LOAD(0);
  K1_WRITE(0);
  __syncthreads();
  for (int t = 0; t < 15; ++t) {
    K1_LOAD((t + 1) * 32);   // issue next tile's global loads
    K1_COMPUTE(t & 1);       // ~2048 issue-cyc/wave hides load latency
    K1_WRITE((t & 1) ^ 1);   // vmcnt drain lands here, post-compute
    __syncthreads();
  }
  K1_COMPUTE(1);

#pragma unroll
  for (int i = 0; i < 8; ++i) {
    const size_t row = (size_t)(nbase + 4 * ty + (i & 3) + 64 * (i >> 2));
    const float4 v = {acc[i][0].x, acc[i][0].y, acc[i][1].x, acc[i][1].y};
    *reinterpret_cast<float4*>(xp + row * 512 + obase + 4 * tx) = v;
    ushort4 u = {f2bf(v.x), f2bf(v.y), f2bf(v.z), f2bf(v.w)};
    *reinterpret_cast<ushort4*>(xp16 + row * 512 + obase + 4 * tx) = u;
  }
#undef K1_LOAD
#undef K1_WRITE
#undef K1_COMPUTE
}

// K2: 128x128 tile, 4 waves (2x2), BK=32, 2-phase dbuf staging, u32-key epilogue.
__global__ __launch_bounds__(256) void score_kernel(const unsigned short* __restrict__ xp16,
                                                    unsigned int* __restrict__ cand) {
  __shared__ unsigned short lA[2][128 * 32];
  __shared__ unsigned short lB[2][128 * 32];
  const int tid = threadIdx.x;
  const int wid = tid >> 6, lane = tid & 63;
  const int lr = lane & 15, kg = lane >> 4;  // frag row / k-group
  const int b = blockIdx.x & 7;              // batch -> XCD pin
  const int rem = blockIdx.x >> 3;
  const int tn = rem & 15, tm = rem >> 4;
  const int nbase = tn * 128, mbase = tm * 128;
  const unsigned short* Xb = xp16 + (size_t)b * 2048 * 512;
  const int wr = wid >> 1, wc = wid & 1;     // wave -> 64x64 quadrant

  // staging map: thread t -> row t>>2 (+64 for second call), bf16 col (t&3)*8.
  // LDS dest is linear (wave-uniform base + lane*16B) matching [row][32] layout.
  const int srow = tid >> 2;
  const int scol = (tid & 3) * 8;
  const unsigned short* gA0 = Xb + (size_t)(nbase + srow) * 512 + scol;
  const unsigned short* gA1 = Xb + (size_t)(nbase + 64 + srow) * 512 + scol;
  const unsigned short* gB0 = Xb + (size_t)(mbase + srow) * 512 + scol;
  const unsigned short* gB1 = Xb + (size_t)(mbase + 64 + srow) * 512 + scol;

  f32x4 acc[4][4] = {};

#define STAGE(KB, BUF)                                    \
  do {                                                    \
    gload_lds16(gA0 + (KB), &lA[BUF][wid * 512]);         \
    gload_lds16(gA1 + (KB), &lA[BUF][2048 + wid * 512]);  \
    gload_lds16(gB0 + (KB), &lB[BUF][wid * 512]);         \
    gload_lds16(gB1 + (KB), &lB[BUF][2048 + wid * 512]);  \
  } while (0)

#define COMPUTE(BUF)                                                                   \
  do {                                                                                 \
    bf16x8 af[4], bfr[4];                                                              \
    _Pragma("unroll") for (int i2 = 0; i2 < 4; ++i2) {                                 \
      af[i2] = *reinterpret_cast<const bf16x8*>(&lA[BUF][(wr * 64 + i2 * 16 + lr) * 32 + kg * 8]); \
      bfr[i2] = *reinterpret_cast<const bf16x8*>(&lB[BUF][(wc * 64 + i2 * 16 + lr) * 32 + kg * 8]); \
    }                                                                                  \
    _Pragma("unroll") for (int i2 = 0; i2 < 4; ++i2)                                   \
        _Pragma("unroll") for (int j2 = 0; j2 < 4; ++j2)                               \
            acc[i2][j2] =                                                              \
                __builtin_amdgcn_mfma_f32_16x16x32_bf16(af[i2], bfr[j2], acc[i2][j2], 0, 0, 0); \
  } while (0)

  STAGE(0, 0);
  __syncthreads();  // drain prologue stage
  for (int t = 0; t < 15; ++t) {
    STAGE((t + 1) * 32, (t & 1) ^ 1);  // issue next tile first (overlaps MFMA)
    COMPUTE(t & 1);
    __syncthreads();  // drains vmcnt(0): next tile staged; cur reads done
  }
  COMPUTE(1);

  // Epilogue: C frag layout col=lane&15, row=(lane>>4)*4+reg (per 16x16 frag).
  // Branchless top-2 per wave's 64-col slab via sortable u32 keys.
  const int mcol = mbase + wc * 64 + lr;
#pragma unroll
  for (int i = 0; i < 4; ++i) {
#pragma unroll
    for (int r = 0; r < 4; ++r) {
      const unsigned int x0 = skey(acc[i][0][r], mcol + 0);
      const unsigned int x1 = skey(acc[i][1][r], mcol + 16);
      const unsigned int x2 = skey(acc[i][2][r], mcol + 32);
      const unsigned int x3 = skey(acc[i][3][r], mcol + 48);
      const unsigned int lo01 = min(x0, x1), hi01 = max(x0, x1);
      const unsigned int lo23 = min(x2, x3), hi23 = max(x2, x3);
      unsigned int k1 = min(lo01, lo23);
      unsigned int k2 = min(max(lo01, lo23), min(hi01, hi23));
#pragma unroll
      for (int off = 1; off < 16; off <<= 1) {
        const unsigned int o1 = (unsigned int)__shfl_xor((int)k1, off);
        const unsigned int o2 = (unsigned int)__shfl_xor((int)k2, off);
        const unsigned int nk1 = min(k1, o1);
        const unsigned int nk2 = min(max(k1, o1), min(k2, o2));
        k1 = nk1;
        k2 = nk2;
      }
      if (lr == 0) {
        const int n = nbase + wr * 64 + i * 16 + kg * 4 + r;
        const uint2 kv = {k1, k2};
        *reinterpret_cast<uint2*>(cand + ((size_t)b * 2048 + n) * 512 + (tm * 2 + wc) * 2) = kv;
      }
    }
  }
#undef STAGE
#undef COMPUTE
}

// K3: per row: top-8 of 64 keys (u32-min butterfly) -> exact f32 rescore ->
// argmin -> write full att row (no memset needed) + h row.
__global__ __launch_bounds__(64) void finalize_kernel(const float* __restrict__ xp,
                                                      float* __restrict__ h,
                                                      float* __restrict__ att) {
  const int l = threadIdx.x;
  const int b = blockIdx.x & 7;  // batch -> XCD pin
  const int n = blockIdx.x >> 3;
  const size_t r = (size_t)b * 2048 + n;

  // own-row key scratch (written by K2 into h region); keys unique per row.
  unsigned int key = reinterpret_cast<const unsigned int*>(h + r * 512)[l];
  int wsel[8];
#pragma unroll
  for (int t = 0; t < 8; ++t) {
    unsigned int m = key;
#pragma unroll
    for (int off = 1; off < 64; off <<= 1)
      m = min(m, (unsigned int)__shfl_xor((int)m, off));
    wsel[t] = (int)(m & 0x7FFu);
    if (key == m) key = 0xFFFFFFFFu;  // invalidate winner
  }

  const float* xb = xp + (size_t)b * 2048 * 512;
  const float* xn = xb + (size_t)n * 512;
  const float4 q0 = reinterpret_cast<const float4*>(xn)[2 * l];
  const float4 q1 = reinterpret_cast<const float4*>(xn)[2 * l + 1];

  float bestv = FLT_MAX;
  int besti = 0x7fffffff;
#pragma unroll
  for (int t = 0; t < 8; ++t) {
    const float* xm = xb + (size_t)wsel[t] * 512;
    const float4 p0 = reinterpret_cast<const float4*>(xm)[2 * l];
    const float4 p1 = reinterpret_cast<const float4*>(xm)[2 * l + 1];
    float s = 0.f;
    s = fmaf(q0.x, p0.x, s); s = fmaf(q0.y, p0.y, s);
    s = fmaf(q0.z, p0.z, s); s = fmaf(q0.w, p0.w, s);
    s = fmaf(q1.x, p1.x, s); s = fmaf(q1.y, p1.y, s);
    s = fmaf(q1.z, p1.z, s); s = fmaf(q1.w, p1.w, s);
#pragma unroll
    for (int off = 1; off < 64; off <<= 1) s += __shfl_xor(s, off);
    if (s < bestv || (s == bestv && wsel[t] < besti)) { bestv = s; besti = wsel[t]; }
  }

  // h row = xp[b, besti, :]
  const float* xs = xb + (size_t)besti * 512;
  const float4 w0 = reinterpret_cast<const float4*>(xs)[2 * l];
  const float4 w1 = reinterpret_cast<const float4*>(xs)[2 * l + 1];
  float* hrow = h + r * 512;
  reinterpret_cast<float4*>(hrow)[2 * l] = w0;
  reinterpret_cast<float4*>(hrow)[2 * l + 1] = w1;

  // att row: zeros + one-hot at besti
  float* arow = att + r * 2048;
#pragma unroll
  for (int s = 0; s < 8; ++s) {
    const int cbase = s * 256 + l * 4;
    float4 v;
    v.x = (cbase + 0 == besti) ? 1.0f : 0.0f;
    v.y = (cbase + 1 == besti) ? 1.0f : 0.0f;
    v.z = (cbase + 2 == besti) ? 1.0f : 0.0f;
    v.w = (cbase + 3 == besti) ? 1.0f : 0.0f;
    reinterpret_cast<float4*>(arow)[s * 64 + l] = v;
  }
}

extern "C" void kernel_launch(void* const* d_in, const int* in_sizes, int n_in,
                              void* d_out, int out_size, void* d_ws, size_t ws_size,
                              hipStream_t stream) {
  const float* x = (const float*)d_in[0];  // [8,2048,512] f32
  const float* W = (const float*)d_in[1];  // [512,512] f32
  float* out = (float*)d_out;
  float* h = out;                              // [8,2048,512]
  float* att = out + (size_t)8 * 2048 * 512;   // [8,2048,2048]
  float* xp = (float*)d_ws;                    // 32 MB f32
  // bf16 xp in the LAST 16MB of the att region (dead before att is written)
  unsigned short* xp16 = (unsigned short*)(att + ((size_t)32 - 4) * 1024 * 1024);

  dim3 gridA(16384 / 128, 512 / 64);
  hipLaunchKernelGGL(gemm_xw_kernel, gridA, dim3(256), 0, stream, x, W, xp, xp16);

  // key scratch = first 256B of each h row; grid = 8 batches x 16x16 tiles
  hipLaunchKernelGGL(score_kernel, dim3(8 * 16 * 16), dim3(256), 0, stream, xp16,
                     (unsigned int*)h);

  hipLaunchKernelGGL(finalize_kernel, dim3(16384), dim3(64), 0, stream, xp, h, att);
}